// Round 4
// baseline (73.466 us; speedup 1.0000x reference)
//
#include <hip/hip_runtime.h>

// Stein layer, fused single kernel, 2 row-tiles/wave. B=65536, D=32, H=128.
// out[r] = sum_k [ c_k - h_k*(h_k*c_k + v_k) ] - x.b2 + theta0
//   z = x W1 + b1 (dual-bf16 MFMA: aHi*bHi + aHi*bLo + aLo*bHi), h = tanh(z)
//   v = x W2^T (single bf16 MFMA); x.b2 via augmented col 128 of W2^T
//   c_k = sum_i W1[i,k] W2[k,i] (fp32, per-block during pack)
// Grid: 256 blocks x 512 threads (8 waves). Each wave: 32 rows (2 MFMA
// row-tiles sharing one set of B-fragment LDS reads). 1 block/CU.

#define NROWS 65536
#define DD 32
#define HH 128
#define NTILE 25  // 8 W1hi + 8 W1lo + 9 W2T(+b2 augmented)

typedef __attribute__((ext_vector_type(8))) short short8;
typedef __attribute__((ext_vector_type(4))) float f32x4;

static __device__ __forceinline__ unsigned short f2bf(float f) {
    unsigned u = __float_as_uint(f);
    u += 0x7fff + ((u >> 16) & 1);  // RNE
    return (unsigned short)(u >> 16);
}
static __device__ __forceinline__ float bf2f(unsigned short h) {
    return __uint_as_float(((unsigned)h) << 16);
}

__global__ __launch_bounds__(512, 2) void stein_fused(
    const float* __restrict__ x, const float* __restrict__ W1,
    const float* __restrict__ b1, const float* __restrict__ W2,
    const float* __restrict__ b2, const float* __restrict__ theta,
    float* __restrict__ out) {
    __shared__ unsigned short lb[NTILE * 512];  // B-frags: lb[t*512 + l*8 + j]
    __shared__ float2 cb[HH];                   // (c_k, b1_k) pairs

    const int tid = threadIdx.x;
    const int lane = tid & 63;
    const int wv = tid >> 6;       // 8 waves
    const int quad = lane >> 4;
    const int cl = lane & 15;
    const int rowbase = blockIdx.x * 256 + wv * 32;  // 256 blocks * 256 rows

    // Prefetch both row-tiles' x (A[m=cl][k=quad*8+j]) before the pack phase.
    const float* xr0 = x + (size_t)(rowbase + cl) * DD + quad * 8;
    const float* xr1 = x + (size_t)(rowbase + 16 + cl) * DD + quad * 8;
    const float4 x00 = *(const float4*)xr0;
    const float4 x01 = *(const float4*)(xr0 + 4);
    const float4 x10 = *(const float4*)xr1;
    const float4 x11 = *(const float4*)(xr1 + 4);

    // ---- Pack phase ----
    // Fragment addressing: tile t, col cc, k: lb[t*512 + ((k>>3)*16+cc)*8 + (k&7)]
    if (tid < 256) {
        // W1 column n: tiles n>>4 (hi) and 8+(n>>4) (lo).
        const int n = tid & 127;
        const int half = tid >> 7;
        const int t = n >> 4, cc = n & 15;
#pragma unroll
        for (int g = 0; g < 2; ++g) {
            const int kg = half * 2 + g;  // k-group of 8
            short8 hi, lo;
#pragma unroll
            for (int j = 0; j < 8; ++j) {
                const float w = W1[(kg * 8 + j) * HH + n];
                const unsigned short h = f2bf(w);
                hi[j] = (short)h;
                lo[j] = (short)f2bf(w - bf2f(h));
            }
            *(short8*)(lb + t * 512 + (kg * 16 + cc) * 8) = hi;
            *(short8*)(lb + (8 + t) * 512 + (kg * 16 + cc) * 8) = lo;
        }
    } else if (tid < 384) {
        // W2 row n -> W2T column n (tile 16+(n>>4)).
        const int n = tid - 256;
        const int t2 = 16 + (n >> 4), cc = n & 15;
        const float4* wr = (const float4*)(W2 + n * DD);
#pragma unroll
        for (int g = 0; g < 4; ++g) {
            const float4 f0 = wr[2 * g];
            const float4 f1 = wr[2 * g + 1];
            short8 v;
            v[0] = (short)f2bf(f0.x); v[1] = (short)f2bf(f0.y);
            v[2] = (short)f2bf(f0.z); v[3] = (short)f2bf(f0.w);
            v[4] = (short)f2bf(f1.x); v[5] = (short)f2bf(f1.y);
            v[6] = (short)f2bf(f1.z); v[7] = (short)f2bf(f1.w);
            *(short8*)(lb + t2 * 512 + (g * 16 + cc) * 8) = v;
        }
    } else {
        // c_k + b1 pairs, and tile 24 (b2 augmentation).
        const int u = tid - 384;  // 0..127
        float row[DD];
        const float4* wr = (const float4*)(W2 + u * DD);
#pragma unroll
        for (int q = 0; q < 8; ++q) {
            const float4 f = wr[q];
            row[4 * q + 0] = f.x; row[4 * q + 1] = f.y;
            row[4 * q + 2] = f.z; row[4 * q + 3] = f.w;
        }
        float acc = 0.f;
#pragma unroll
        for (int k = 0; k < DD; ++k) acc = fmaf(W1[k * HH + u], row[k], acc);
        cb[u] = make_float2(acc, b1[u]);
        if (u < 16) {
#pragma unroll
            for (int g = 0; g < 4; ++g) {
                short8 v;
#pragma unroll
                for (int j = 0; j < 8; ++j)
                    v[j] = (u == 0) ? (short)f2bf(b2[g * 8 + j]) : (short)0;
                *(short8*)(lb + 24 * 512 + (g * 16 + u) * 8) = v;
            }
        }
    }
    __syncthreads();

    // ---- MFMA phase: two row-tiles share every B-fragment read ----
    short8 aHi0, aLo0, aHi1, aLo1;
    {
        const float xv0[8] = {x00.x, x00.y, x00.z, x00.w, x01.x, x01.y, x01.z, x01.w};
        const float xv1[8] = {x10.x, x10.y, x10.z, x10.w, x11.x, x11.y, x11.z, x11.w};
#pragma unroll
        for (int j = 0; j < 8; ++j) {
            unsigned short h0 = f2bf(xv0[j]);
            aHi0[j] = (short)h0;
            aLo0[j] = (short)f2bf(xv0[j] - bf2f(h0));
            unsigned short h1 = f2bf(xv1[j]);
            aHi1[j] = (short)h1;
            aLo1[j] = (short)f2bf(xv1[j] - bf2f(h1));
        }
    }

    const f32x4 zero = {0.f, 0.f, 0.f, 0.f};
    float sa0[4] = {0.f, 0.f, 0.f, 0.f};
    float sa1[4] = {0.f, 0.f, 0.f, 0.f};

#pragma unroll
    for (int t = 0; t < 8; ++t) {
        const short8 bH = *(const short8*)(lb + t * 512 + lane * 8);
        const short8 bL = *(const short8*)(lb + (8 + t) * 512 + lane * 8);
        const short8 bW = *(const short8*)(lb + (16 + t) * 512 + lane * 8);
        const float2 cbv = cb[t * 16 + cl];
        f32x4 z0 = zero, z1 = zero;
        z0 = __builtin_amdgcn_mfma_f32_16x16x32_bf16(aLo0, bH, z0, 0, 0, 0);
        z1 = __builtin_amdgcn_mfma_f32_16x16x32_bf16(aLo1, bH, z1, 0, 0, 0);
        z0 = __builtin_amdgcn_mfma_f32_16x16x32_bf16(aHi0, bL, z0, 0, 0, 0);
        z1 = __builtin_amdgcn_mfma_f32_16x16x32_bf16(aHi1, bL, z1, 0, 0, 0);
        z0 = __builtin_amdgcn_mfma_f32_16x16x32_bf16(aHi0, bH, z0, 0, 0, 0);
        z1 = __builtin_amdgcn_mfma_f32_16x16x32_bf16(aHi1, bH, z1, 0, 0, 0);
        const f32x4 v0 = __builtin_amdgcn_mfma_f32_16x16x32_bf16(aHi0, bW, zero, 0, 0, 0);
        const f32x4 v1 = __builtin_amdgcn_mfma_f32_16x16x32_bf16(aHi1, bW, zero, 0, 0, 0);
#pragma unroll
        for (int r = 0; r < 4; ++r) {
            {
                const float zz = z0[r] + cbv.y;
                const float e = __expf(2.f * zz);  // inf->h=1, 0->h=-1: exact
                const float h = fmaf(-2.f, __builtin_amdgcn_rcpf(e + 1.f), 1.f);
                sa0[r] += cbv.x - h * fmaf(h, cbv.x, v0[r]);
            }
            {
                const float zz = z1[r] + cbv.y;
                const float e = __expf(2.f * zz);
                const float h = fmaf(-2.f, __builtin_amdgcn_rcpf(e + 1.f), 1.f);
                sa1[r] += cbv.x - h * fmaf(h, cbv.x, v1[r]);
            }
        }
    }
    {  // Augmented tile 24: x.b2 lands in col 128 (cl==0), others exact zero.
        const short8 bW = *(const short8*)(lb + 24 * 512 + lane * 8);
        const f32x4 v0 = __builtin_amdgcn_mfma_f32_16x16x32_bf16(aHi0, bW, zero, 0, 0, 0);
        const f32x4 v1 = __builtin_amdgcn_mfma_f32_16x16x32_bf16(aHi1, bW, zero, 0, 0, 0);
#pragma unroll
        for (int r = 0; r < 4; ++r) { sa0[r] -= v0[r]; sa1[r] -= v1[r]; }
    }

    // Reduce over the 16 output columns (cl bits of the lane id).
#pragma unroll
    for (int r = 0; r < 4; ++r) {
#pragma unroll
        for (int m = 1; m < 16; m <<= 1) {
            sa0[r] += __shfl_xor(sa0[r], m, 64);
            sa1[r] += __shfl_xor(sa1[r], m, 64);
        }
    }

    // C/D rows: row = quad*4 + reg -> lane cl==0 stores 4 consecutive rows.
    if (cl == 0) {
        const float th = theta[0];
        float4 o0, o1;
        o0.x = sa0[0] + th; o0.y = sa0[1] + th;
        o0.z = sa0[2] + th; o0.w = sa0[3] + th;
        o1.x = sa1[0] + th; o1.y = sa1[1] + th;
        o1.z = sa1[2] + th; o1.w = sa1[3] + th;
        *(float4*)(out + rowbase + quad * 4) = o0;
        *(float4*)(out + rowbase + 16 + quad * 4) = o1;
    }
}

extern "C" void kernel_launch(void* const* d_in, const int* in_sizes, int n_in,
                              void* d_out, int out_size, void* d_ws, size_t ws_size,
                              hipStream_t stream) {
    const float* x = (const float*)d_in[0];
    const float* W1 = (const float*)d_in[1];
    const float* b1 = (const float*)d_in[2];
    const float* W2 = (const float*)d_in[3];
    const float* b2 = (const float*)d_in[4];
    const float* theta = (const float*)d_in[5];
    float* out = (float*)d_out;

    stein_fused<<<NROWS / 256, 512, 0, stream>>>(x, W1, b1, W2, b2, theta, out);
}

// Round 5
// 71.809 us; speedup vs baseline: 1.0231x; 1.0231x over previous
//
#include <hip/hip_runtime.h>

// Stein layer, fused single kernel. B=65536, D=32, H=128.
// out[r] = sum_k [ c_k - h_k*(h_k*c_k + v_k) ] - x.b2 + theta0
//   z = x W1 + b1 (dual-bf16 MFMA: aHi*bHi + aHi*bLo + aLo*bHi), h = tanh(z)
//   v = x W2^T (single bf16 MFMA); x.b2 via augmented col 128 of W2^T
//   c_k = sum_i W1[i,k] W2[k,i] (fp32, per-block during pack)
// Grid: 1024 blocks x 256 threads (4 waves, 16 rows/wave).
// __launch_bounds__(256,5): 5 blocks/CU = 20 waves/CU (latency-bound kernel;
// R4 showed fatter waves (fewer/CU) regress, so go thinner+more).

#define NROWS 65536
#define DD 32
#define HH 128
#define NTILE 25  // 8 W1hi + 8 W1lo + 9 W2T(+b2 augmented)

typedef __attribute__((ext_vector_type(8))) short short8;
typedef __attribute__((ext_vector_type(4))) float f32x4;

static __device__ __forceinline__ unsigned short f2bf(float f) {
    unsigned u = __float_as_uint(f);
    u += 0x7fff + ((u >> 16) & 1);  // RNE
    return (unsigned short)(u >> 16);
}
static __device__ __forceinline__ float bf2f(unsigned short h) {
    return __uint_as_float(((unsigned)h) << 16);
}

__global__ __launch_bounds__(256, 5) void stein_fused(
    const float* __restrict__ x, const float* __restrict__ W1,
    const float* __restrict__ b1, const float* __restrict__ W2,
    const float* __restrict__ b2, const float* __restrict__ theta,
    float* __restrict__ out) {
    __shared__ unsigned short lb[NTILE * 512];  // B-frags: lb[t*512 + l*8 + j]
    __shared__ float2 cb[HH];                   // (c_k, b1_k) pairs

    const int tid = threadIdx.x;
    const int lane = tid & 63;
    const int wv = tid >> 6;       // 4 waves
    const int quad = lane >> 4;
    const int cl = lane & 15;
    const int rowbase = blockIdx.x * 64 + wv * 16;  // 1024 blocks * 64 rows

    // Prefetch this wave's x (A[m=cl][k=quad*8+j]) before the pack phase.
    const float* xr = x + (size_t)(rowbase + cl) * DD + quad * 8;
    const float4 x0 = *(const float4*)xr;
    const float4 x1 = *(const float4*)(xr + 4);

    // ---- Pack phase (all 256 threads busy) ----
    // Fragment addressing: tile t, col cc, k: lb[t*512 + ((k>>3)*16+cc)*8 + (k&7)]
    if (tid < 128) {
        // W1 column n -> tiles n>>4 (hi) and 8+(n>>4) (lo), all 4 k-groups.
        const int n = tid;
        const int t = n >> 4, cc = n & 15;
#pragma unroll
        for (int kg = 0; kg < 4; ++kg) {
            short8 hi, lo;
#pragma unroll
            for (int j = 0; j < 8; ++j) {
                const float w = W1[(kg * 8 + j) * HH + n];
                const unsigned short h = f2bf(w);
                hi[j] = (short)h;
                lo[j] = (short)f2bf(w - bf2f(h));
            }
            *(short8*)(lb + t * 512 + (kg * 16 + cc) * 8) = hi;
            *(short8*)(lb + (8 + t) * 512 + (kg * 16 + cc) * 8) = lo;
        }
    } else {
        // W2 row n -> W2T column n (tile 16+(n>>4)); c_n + b1_n; tile 24.
        const int n = tid - 128;
        const int t2 = 16 + (n >> 4), cc = n & 15;
        float row[DD];
        const float4* wr = (const float4*)(W2 + n * DD);
#pragma unroll
        for (int q = 0; q < 8; ++q) {
            const float4 f = wr[q];
            row[4 * q + 0] = f.x; row[4 * q + 1] = f.y;
            row[4 * q + 2] = f.z; row[4 * q + 3] = f.w;
        }
#pragma unroll
        for (int g = 0; g < 4; ++g) {
            short8 v;
#pragma unroll
            for (int j = 0; j < 8; ++j) v[j] = (short)f2bf(row[g * 8 + j]);
            *(short8*)(lb + t2 * 512 + (g * 16 + cc) * 8) = v;
        }
        float acc = 0.f;
#pragma unroll
        for (int k = 0; k < DD; ++k) acc = fmaf(W1[k * HH + n], row[k], acc);
        cb[n] = make_float2(acc, b1[n]);
        if (n < 16) {
            // Tile 24: augmented col 128+n -> b2 (n==0) else zeros.
#pragma unroll
            for (int g = 0; g < 4; ++g) {
                short8 v;
#pragma unroll
                for (int j = 0; j < 8; ++j)
                    v[j] = (n == 0) ? (short)f2bf(b2[g * 8 + j]) : (short)0;
                *(short8*)(lb + 24 * 512 + (g * 16 + n) * 8) = v;
            }
        }
    }
    __syncthreads();

    // ---- MFMA phase ----
    const float xv[8] = {x0.x, x0.y, x0.z, x0.w, x1.x, x1.y, x1.z, x1.w};
    short8 aHi, aLo;
#pragma unroll
    for (int j = 0; j < 8; ++j) {
        const unsigned short h = f2bf(xv[j]);
        aHi[j] = (short)h;
        aLo[j] = (short)f2bf(xv[j] - bf2f(h));
    }

    const f32x4 zero = {0.f, 0.f, 0.f, 0.f};
    float sa[4] = {0.f, 0.f, 0.f, 0.f};

#pragma unroll
    for (int t = 0; t < 8; ++t) {
        const short8 bH = *(const short8*)(lb + t * 512 + lane * 8);
        const short8 bL = *(const short8*)(lb + (8 + t) * 512 + lane * 8);
        const short8 bW = *(const short8*)(lb + (16 + t) * 512 + lane * 8);
        const float2 cbv = cb[t * 16 + cl];
        f32x4 z = zero;
        z = __builtin_amdgcn_mfma_f32_16x16x32_bf16(aLo, bH, z, 0, 0, 0);
        z = __builtin_amdgcn_mfma_f32_16x16x32_bf16(aHi, bL, z, 0, 0, 0);
        z = __builtin_amdgcn_mfma_f32_16x16x32_bf16(aHi, bH, z, 0, 0, 0);
        const f32x4 v = __builtin_amdgcn_mfma_f32_16x16x32_bf16(aHi, bW, zero, 0, 0, 0);
#pragma unroll
        for (int r = 0; r < 4; ++r) {
            const float zz = z[r] + cbv.y;
            const float e = __expf(2.f * zz);  // inf->h=1, 0->h=-1: exact
            const float h = fmaf(-2.f, __builtin_amdgcn_rcpf(e + 1.f), 1.f);
            sa[r] += cbv.x - h * fmaf(h, cbv.x, v[r]);  // c - h^2 c - h v
        }
    }
    {  // Augmented tile 24: x.b2 lands in col 128 (cl==0), others exact zero.
        const short8 bW = *(const short8*)(lb + 24 * 512 + lane * 8);
        const f32x4 v = __builtin_amdgcn_mfma_f32_16x16x32_bf16(aHi, bW, zero, 0, 0, 0);
#pragma unroll
        for (int r = 0; r < 4; ++r) sa[r] -= v[r];
    }

    // Reduce over the 16 output columns (cl bits of the lane id).
#pragma unroll
    for (int r = 0; r < 4; ++r) {
#pragma unroll
        for (int m = 1; m < 16; m <<= 1) sa[r] += __shfl_xor(sa[r], m, 64);
    }

    // C/D rows: row = quad*4 + reg -> lane cl==0 stores 4 consecutive rows.
    if (cl == 0) {
        const float th = theta[0];
        float4 o;
        o.x = sa[0] + th;
        o.y = sa[1] + th;
        o.z = sa[2] + th;
        o.w = sa[3] + th;
        *(float4*)(out + rowbase + quad * 4) = o;
    }
}

extern "C" void kernel_launch(void* const* d_in, const int* in_sizes, int n_in,
                              void* d_out, int out_size, void* d_ws, size_t ws_size,
                              hipStream_t stream) {
    const float* x = (const float*)d_in[0];
    const float* W1 = (const float*)d_in[1];
    const float* b1 = (const float*)d_in[2];
    const float* W2 = (const float*)d_in[3];
    const float* b2 = (const float*)d_in[4];
    const float* theta = (const float*)d_in[5];
    float* out = (float*)d_out;

    stein_fused<<<NROWS / 64, 256, 0, stream>>>(x, W1, b1, W2, b2, theta, out);
}